// Round 9
// baseline (362.422 us; speedup 1.0000x reference)
//
#include <hip/hip_runtime.h>

// ---- problem dims (fixed by setup_inputs) ----
#define N_NODES 131072
#define DIM     128
#define NG      2048
#define HD      512

typedef unsigned short u16;
typedef _Float16 half8 __attribute__((ext_vector_type(8)));
typedef float  f32x4  __attribute__((ext_vector_type(4)));

// ---- static device scratch (referenced ONLY from device code) ----
__device__ u16   g_wm[(size_t)HD * DIM];          // W_m fp16 (rows j, cols d)
__device__ u16   g_wmT[(size_t)DIM * HD];         // W_m^T fp16 (rows d, cols j)
__device__ u16   g_wgf[(size_t)2048 * 640];       // [perm(Wih1+Whh) | perm(Wfold)] fp16
__device__ u16   g_wih2[(size_t)2048 * 512];      // perm(Wih[:,512:]) fp16
__device__ float g_bc[2048];                      // perm(b_ih+b_hh) fp32
__device__ float g_bf[2048];                      // perm(Wih2 @ b_m) fp32
__device__ float g_gh[2048];                      // perm((Wih1+Whh) @ h1) fp32
__device__ float g_c0[512];                       // c1 (graph-independent) fp32
__device__ float g_w20[128];                      // w2_1 = h1 @ W_m fp32
__device__ float g_tp[NG];                        // t' = sum a_n
__device__ u16   g_Acat[(size_t)NG * 640];        // [h2(512) | S'(128)] fp16
__device__ u16   g_h3[(size_t)NG * HD];           // h3 fp16 (separate buffer)
__device__ float g_c[(size_t)NG * HD];
__device__ int   g_start[NG + 1];
__device__ int   g_isbf16;
__device__ int   g_idx64;

__device__ __forceinline__ float bf2f(u16 u) {
  unsigned v = ((unsigned)u) << 16;
  float f; __builtin_memcpy(&f, &v, 4); return f;
}
__device__ __forceinline__ float u2f_hi(unsigned u) {
  unsigned v = u & 0xFFFF0000u;
  float f; __builtin_memcpy(&f, &v, 4); return f;
}
__device__ __forceinline__ float u2f_lo(unsigned u) {
  unsigned v = u << 16;
  float f; __builtin_memcpy(&f, &v, 4); return f;
}
__device__ __forceinline__ u16 f2bf(float f) {
  unsigned u; __builtin_memcpy(&u, &f, 4);
  u += 0x7FFFu + ((u >> 16) & 1u);
  return (u16)(u >> 16);
}
__device__ __forceinline__ u16 f2h(float f) {
  _Float16 h = (_Float16)f; u16 u; __builtin_memcpy(&u, &h, 2); return u;
}
__device__ __forceinline__ float h2f(u16 u) {
  _Float16 h; __builtin_memcpy(&h, &u, 2); return (float)h;
}
__device__ __forceinline__ float rdf(const void* p, int i) {
  return g_isbf16 ? bf2f(((const u16*)p)[i]) : ((const float*)p)[i];
}

#define GLD16(gp, lp) __builtin_amdgcn_global_load_lds(                          \
    (const __attribute__((address_space(1))) void*)(gp),                         \
    (__attribute__((address_space(3))) void*)(lp), 16, 0, 0)

// ---- dtype detection ----
__global__ void k_detect(const void* feat, const void* gi) {
  __shared__ int cnt;
  if (threadIdx.x == 0) cnt = 0;
  __syncthreads();
  u16 u = ((const u16*)feat)[threadIdx.x];
  float v = bf2f(u);
  float a = fabsf(v);
  int ok = (v == v) && a >= 1e-6f && a <= 1e6f;
  atomicAdd(&cnt, ok);
  __syncthreads();
  if (threadIdx.x == 0) {
    g_isbf16 = (cnt >= 230);
    g_idx64 = (((const int*)gi)[N_NODES - 1] == 0);
  }
}

// ---- pair counts. gate-row permutation: permuted row n = 4*j + q ----
#define NWP ((size_t)HD * DIM / 2)
#define NWT ((size_t)DIM * HD / 2)
#define NW1 ((size_t)2048 * 512 / 2)
#define NW2 ((size_t)2048 * 512 / 2)
#define W_PAIRS (NWP + NWT + NW1 + NW2)

// ---- S0: weight conversions (grid-stride) + per-graph start offsets ----
__global__ __launch_bounds__(256) void k_s0(const void* gidxv, const void* wmp,
                                            const void* wih, const void* whh) {
  const int t = threadIdx.x;
  for (size_t i = (size_t)blockIdx.x * 256 + t; i < W_PAIRS;
       i += (size_t)gridDim.x * 256) {
    if (i < NWP) {
      float v0, v1;
      if (g_isbf16) {
        unsigned pr = ((const unsigned*)wmp)[i];
        v0 = bf2f((u16)pr); v1 = bf2f((u16)(pr >> 16));
      } else {
        float2 v = ((const float2*)wmp)[i];
        v0 = v.x; v1 = v.y;
      }
      ((unsigned*)g_wm)[i] = (unsigned)f2h(v0) | ((unsigned)f2h(v1) << 16);
    } else if (i < NWP + NWT) {
      size_t p = i - NWP;
      int d = (int)(p >> 8), j = (int)(p & 255) * 2;
      float v0 = rdf(wmp, j * DIM + d);
      float v1 = rdf(wmp, (j + 1) * DIM + d);
      ((unsigned*)g_wmT)[(size_t)d * 256 + (j >> 1)] =
          (unsigned)f2h(v0) | ((unsigned)f2h(v1) << 16);
    } else if (i < NWP + NWT + NW1) {
      size_t p = i - NWP - NWT;
      int n = (int)(p >> 8), kp = (int)(p & 255), k = kp * 2;
      int orig = (n & 3) * 512 + (n >> 2);
      float v0 = rdf(wih, orig * 1024 + k)     + rdf(whh, orig * 512 + k);
      float v1 = rdf(wih, orig * 1024 + k + 1) + rdf(whh, orig * 512 + k + 1);
      ((unsigned*)g_wgf)[(size_t)n * 320 + kp] =
          (unsigned)f2h(v0) | ((unsigned)f2h(v1) << 16);
    } else {
      size_t p = i - NWP - NWT - NW1;
      int n = (int)(p >> 8), kp = (int)(p & 255), k = kp * 2;
      int orig = (n & 3) * 512 + (n >> 2);
      float v0 = rdf(wih, orig * 1024 + 512 + k);
      float v1 = rdf(wih, orig * 1024 + 512 + k + 1);
      ((unsigned*)g_wih2)[(size_t)n * 256 + kp] =
          (unsigned)f2h(v0) | ((unsigned)f2h(v1) << 16);
    }
  }
  if (blockIdx.x < 512) {
    int n = blockIdx.x * 256 + t;
    const int idx64 = g_idx64;
    int gg = idx64 ? (int)((const long long*)gidxv)[n] : ((const int*)gidxv)[n];
    if (n == 0) {
      for (int x = 0; x <= gg; ++x) g_start[x] = 0;
    } else {
      int gp = idx64 ? (int)((const long long*)gidxv)[n - 1] : ((const int*)gidxv)[n - 1];
      for (int x = gp + 1; x <= gg; ++x) g_start[x] = n;
    }
    if (n == N_NODES - 1) {
      for (int x = gg + 1; x <= NG; ++x) g_start[x] = N_NODES;
    }
  }
}

// ---- S1: bc/bf/gh vectors (blocks 0..127), Wfold GEMM (128..191), c0/w20 (192) ----
__global__ __launch_bounds__(256) void k_s1(const void* bih, const void* bhh,
                                            const void* bm) {
  alignas(16) __shared__ char smem[16384];
  const int t = threadIdx.x, b = blockIdx.x;
  if (b < 128) {
    float* s_bm = (float*)smem;                    // [512]
    float* s_h0 = s_bm + 512;                      // [512]
    for (int p = t; p < 512; p += 256) {
      s_bm[p] = rdf(bm, p);
      float xi = rdf(bih, p)        + rdf(bhh, p);
      float xg = rdf(bih, p + 1024) + rdf(bhh, p + 1024);
      float xo = rdf(bih, p + 1536) + rdf(bhh, p + 1536);
      float si = 1.f / (1.f + __expf(-xi));
      float tg = tanhf(xg);
      float so = 1.f / (1.f + __expf(-xo));
      s_h0[p] = so * tanhf(si * tg);
    }
    __syncthreads();
    const int rloc = t >> 4, k = t & 15;           // 16 rows/block, 16 lanes/row
    const int n = b * 16 + rloc;
    float sbf = 0.f, sgh = 0.f;
#pragma unroll
    for (int j = 0; j < 4; ++j) {
      const int e = k * 8 + j * 128;
      half8 w2v = *(const half8*)(g_wih2 + (size_t)n * 512 + e);
      half8 w1v = *(const half8*)(g_wgf  + (size_t)n * 640 + e);
#pragma unroll
      for (int d = 0; d < 8; ++d) {
        sbf += (float)w2v[d] * s_bm[e + d];
        sgh += (float)w1v[d] * s_h0[e + d];
      }
    }
#pragma unroll
    for (int o = 1; o < 16; o <<= 1) {
      sbf += __shfl_xor(sbf, o, 64);
      sgh += __shfl_xor(sgh, o, 64);
    }
    if (k == 0) {
      const int orig = (n & 3) * 512 + (n >> 2);
      g_bf[n] = sbf;
      g_gh[n] = sgh;
      g_bc[n] = rdf(bih, orig) + rdf(bhh, orig);
    }
  } else if (b < 192) {
    u16* As = (u16*)smem;                          // [64*64]
    u16* Bs = As + 4096;
    const int bx = b - 128;
    const int lid = t & 63, w = t >> 6;
    const int m0 = (bx & 31) * 64, n0 = (bx >> 5) * 64;
    const int rr = lid & 15, quad = lid >> 4;
    const int rsub = lid >> 3;
    const int cs = (lid & 7) ^ rsub;
    const int wm = (w >> 1) * 32, wn = (w & 1) * 32;
    f32x4 acc[2][2] = {};
    for (int kt = 0; kt < 8; ++kt) {
      const int k0 = kt * 64;
      GLD16(g_wih2 + (size_t)(m0 + w * 16 + rsub) * 512 + k0 + cs * 8, As + (w * 16) * 64);
      GLD16(g_wih2 + (size_t)(m0 + w * 16 + 8 + rsub) * 512 + k0 + cs * 8, As + (w * 16 + 8) * 64);
      GLD16(g_wmT + (size_t)(n0 + w * 16 + rsub) * 512 + k0 + cs * 8, Bs + (w * 16) * 64);
      GLD16(g_wmT + (size_t)(n0 + w * 16 + 8 + rsub) * 512 + k0 + cs * 8, Bs + (w * 16 + 8) * 64);
      __syncthreads();
#pragma unroll
      for (int kk = 0; kk < 2; ++kk) {
        const int qb = kk * 4 + quad;
        const int sw = (qb ^ (rr & 7)) << 3;
        half8 af[2], bfr[2];
#pragma unroll
        for (int i = 0; i < 2; ++i) af[i]  = *(const half8*)(As + (wm + i * 16 + rr) * 64 + sw);
#pragma unroll
        for (int j = 0; j < 2; ++j) bfr[j] = *(const half8*)(Bs + (wn + j * 16 + rr) * 64 + sw);
#pragma unroll
        for (int i = 0; i < 2; ++i)
#pragma unroll
          for (int j = 0; j < 2; ++j)
            acc[i][j] = __builtin_amdgcn_mfma_f32_16x16x32_f16(bfr[j], af[i], acc[i][j], 0, 0, 0);
      }
      __syncthreads();
    }
#pragma unroll
    for (int i = 0; i < 2; ++i)
#pragma unroll
      for (int j = 0; j < 2; ++j) {
        const int row = m0 + wm + i * 16 + rr;
        const int c0 = n0 + wn + j * 16 + quad * 4;
        u16 h4[4];
#pragma unroll
        for (int r = 0; r < 4; ++r) h4[r] = f2h(acc[i][j][r]);
        *(uint2*)(g_wgf + (size_t)row * 640 + 512 + c0) =
            make_uint2((unsigned)h4[0] | ((unsigned)h4[1] << 16),
                       (unsigned)h4[2] | ((unsigned)h4[3] << 16));
      }
  } else if (b == 192) {
    float* s_h   = (float*)smem;                   // [512]
    float* s_red = s_h + 512;                      // [4][128]
    for (int j = t; j < 512; j += 256) {
      float xi = rdf(bih, j)        + rdf(bhh, j);
      float xg = rdf(bih, j + 1024) + rdf(bhh, j + 1024);
      float xo = rdf(bih, j + 1536) + rdf(bhh, j + 1536);
      float si = 1.f / (1.f + __expf(-xi));
      float tg = tanhf(xg);
      float so = 1.f / (1.f + __expf(-xo));
      float cn = si * tg;
      float hn = so * tanhf(cn);
      g_c0[j] = cn;
      s_h[j] = hn;
    }
    __syncthreads();
    const int dg = t & 15, jg = t >> 4;
    float a8[8] = {};
    for (int jj = 0; jj < 32; ++jj) {
      const int j = jg * 32 + jj;
      half8 wv = *(const half8*)(g_wm + (size_t)j * 128 + dg * 8);
      const float hv = s_h[j];
#pragma unroll
      for (int d = 0; d < 8; ++d) a8[d] += hv * (float)wv[d];
    }
#pragma unroll
    for (int d = 0; d < 8; ++d) {
      a8[d] += __shfl_xor(a8[d], 16, 64);
      a8[d] += __shfl_xor(a8[d], 32, 64);
    }
    const int w = t >> 6;
    if ((t & 63) < 16) {
      *(f32x4*)&s_red[w * 128 + dg * 8]     = *(f32x4*)&a8[0];
      *(f32x4*)&s_red[w * 128 + dg * 8 + 4] = *(f32x4*)&a8[4];
    }
    __syncthreads();
    if (t < 128)
      g_w20[t] = s_red[t] + s_red[128 + t] + s_red[256 + t] + s_red[384 + t];
  }
}

// ---- gates GEMM (one 64x64 tile per block) + fused LSTM epilogue.
// h3out=0: new h -> g_Acat h-half (A-reads touch only S' cols, aoff=512).
// h3out=1: new h -> g_h3 (A-reads cover h cols; separate buffer, no race). ----
__global__ __launch_bounds__(256) void k_gemm(int ktiles2, int aoff, int useGh,
                                              int first, int wout, int h3out,
                                              void* __restrict__ out) {
  alignas(16) __shared__ u16 As[2][64 * 64];
  alignas(16) __shared__ u16 Bs[2][64 * 64];
  const int t = threadIdx.x, lid = t & 63, w = t >> 6;
  const int m0 = (blockIdx.x & 31) * 64, n0 = (blockIdx.x >> 5) * 64;
  const int rr = lid & 15, quad = lid >> 4;
  const int rsub = lid >> 3;
  const int cs = (lid & 7) ^ rsub;
  const int wm = (w >> 1) * 32, wn = (w & 1) * 32;
  const int isb = g_isbf16;
  f32x4 acc[2][2] = {};
  for (int kt2 = 0; kt2 < ktiles2; ++kt2) {
#pragma unroll
    for (int b = 0; b < 2; ++b) {
      const int k0 = aoff + (kt2 * 2 + b) * 64;
      GLD16(g_Acat + (size_t)(m0 + w * 16 + rsub) * 640 + k0 + cs * 8, As[b] + (w * 16) * 64);
      GLD16(g_Acat + (size_t)(m0 + w * 16 + 8 + rsub) * 640 + k0 + cs * 8, As[b] + (w * 16 + 8) * 64);
      GLD16(g_wgf  + (size_t)(n0 + w * 16 + rsub) * 640 + k0 + cs * 8, Bs[b] + (w * 16) * 64);
      GLD16(g_wgf  + (size_t)(n0 + w * 16 + 8 + rsub) * 640 + k0 + cs * 8, Bs[b] + (w * 16 + 8) * 64);
    }
    __syncthreads();
#pragma unroll
    for (int b = 0; b < 2; ++b)
#pragma unroll
      for (int kk = 0; kk < 2; ++kk) {
        const int qb = kk * 4 + quad;
        const int sw = (qb ^ (rr & 7)) << 3;
        half8 af[2], bfr[2];
#pragma unroll
        for (int i = 0; i < 2; ++i) af[i]  = *(const half8*)(As[b] + (wm + i * 16 + rr) * 64 + sw);
#pragma unroll
        for (int j = 0; j < 2; ++j) bfr[j] = *(const half8*)(Bs[b] + (wn + j * 16 + rr) * 64 + sw);
#pragma unroll
        for (int i = 0; i < 2; ++i)
#pragma unroll
          for (int j = 0; j < 2; ++j)
            acc[i][j] = __builtin_amdgcn_mfma_f32_16x16x32_f16(bfr[j], af[i], acc[i][j], 0, 0, 0);
      }
    __syncthreads();
  }
#pragma unroll
  for (int i = 0; i < 2; ++i) {
    const int row = m0 + wm + i * 16 + rr;           // graph
    const float tp = g_tp[row];
#pragma unroll
    for (int j = 0; j < 2; ++j) {
      const int c0 = n0 + wn + j * 16 + quad * 4;    // permuted gate col, %4==0
      const int jj = c0 >> 2;                        // hidden index
      float4 bc = *(const float4*)(g_bc + c0);
      float4 bf = *(const float4*)(g_bf + c0);
      float gx = 0.f, gy = 0.f, gz = 0.f, gw = 0.f;
      if (useGh) {
        float4 gh = *(const float4*)(g_gh + c0);
        gx = gh.x; gy = gh.y; gz = gh.z; gw = gh.w;
      }
      float xi = acc[i][j][0] + bc.x + gx + tp * bf.x;
      float xf = acc[i][j][1] + bc.y + gy + tp * bf.y;
      float xg = acc[i][j][2] + bc.z + gz + tp * bf.z;
      float xo = acc[i][j][3] + bc.w + gw + tp * bf.w;
      float si = 1.f / (1.f + __expf(-xi));
      float sf = 1.f / (1.f + __expf(-xf));
      float tg = tanhf(xg);
      float so = 1.f / (1.f + __expf(-xo));
      float cp = first ? g_c0[jj] : g_c[(size_t)row * 512 + jj];
      float cn = sf * cp + si * tg;
      float hn = so * tanhf(cn);
      g_c[(size_t)row * 512 + jj] = cn;
      if (h3out) g_h3[(size_t)row * 512 + jj] = f2h(hn);
      else       g_Acat[(size_t)row * 640 + jj] = f2h(hn);
      if (wout) {
        if (isb) ((u16*)out)[(size_t)row * 1024 + jj] = f2bf(hn);
        else     ((float*)out)[(size_t)row * 1024 + jj] = hn;
      }
    }
  }
}

// ---- attention: one graph per block.
// mode 0: w2 = g_w20. mode 1: w2 = h[g] @ W_m in-block.
// hsel: 0 -> h from g_Acat (stride 640); 1 -> h from g_h3 (stride 512).
// fin=0: S' fp16 -> Acat, t' -> g_tp. fin=1: r = S'@W_m^T + t'*b_m -> out. ----
__global__ __launch_bounds__(256) void k_attn(const void* __restrict__ feat, int mode,
                                              int hsel, int fin,
                                              void* __restrict__ out,
                                              const void* __restrict__ bm) {
  __shared__ float s_m[4], s_l[4];
  __shared__ float s_s[4][DIM];
  __shared__ float s_h[512];
  __shared__ float s_keep[DIM];
  __shared__ float s_tpv[1];
  const int g = blockIdx.x;
  const int t = threadIdx.x, lid = t & 63, wid = t >> 6;
  const int c = lid & 15;                          // 8-col chunk index
  const int slot = lid >> 4;                       // node slot 0..3
  const int israw = g_isbf16;
  const int s = g_start[g], e = g_start[g + 1];
  float w2r[8];
  if (mode) {
    const u16* hsrc = hsel ? g_h3 : g_Acat;        // device-resolved symbols
    const int hstr = hsel ? 512 : 640;
    for (int p = t; p < 512; p += 256)
      s_h[p] = h2f(hsrc[(size_t)g * hstr + p]);
    __syncthreads();
    const int jg = t >> 4;
    float a8[8] = {};
    for (int jj = 0; jj < 32; ++jj) {
      const int j = jg * 32 + jj;
      half8 wv = *(const half8*)(g_wm + (size_t)j * 128 + c * 8);
      const float hv = s_h[j];
#pragma unroll
      for (int d = 0; d < 8; ++d) a8[d] += hv * (float)wv[d];
    }
#pragma unroll
    for (int d = 0; d < 8; ++d) {
      a8[d] += __shfl_xor(a8[d], 16, 64);
      a8[d] += __shfl_xor(a8[d], 32, 64);
    }
    if (lid < 16) {
      *(f32x4*)&s_s[wid][c * 8]     = *(f32x4*)&a8[0];
      *(f32x4*)&s_s[wid][c * 8 + 4] = *(f32x4*)&a8[4];
    }
    __syncthreads();
#pragma unroll
    for (int d = 0; d < 8; ++d)
      w2r[d] = s_s[0][c * 8 + d] + s_s[1][c * 8 + d] +
               s_s[2][c * 8 + d] + s_s[3][c * 8 + d];
    __syncthreads();                               // s_s reused below
  } else {
    *(float4*)(w2r)     = *(const float4*)(g_w20 + c * 8);
    *(float4*)(w2r + 4) = *(const float4*)(g_w20 + c * 8 + 4);
  }
  float mrun = -3.0e38f, lsum = 0.f;
  float racc[8] = {0.f, 0.f, 0.f, 0.f, 0.f, 0.f, 0.f, 0.f};
  for (int nb = s + wid * 4; nb < e; nb += 16) {   // 4 waves x 4 slots
    const int n = nb + slot;
    float fv[8], d;
    if (n < e) {
      if (israw) {
        uint4 q = *(const uint4*)((const u16*)feat + (size_t)n * DIM + c * 8);
        fv[0] = u2f_lo(q.x); fv[1] = u2f_hi(q.x);
        fv[2] = u2f_lo(q.y); fv[3] = u2f_hi(q.y);
        fv[4] = u2f_lo(q.z); fv[5] = u2f_hi(q.z);
        fv[6] = u2f_lo(q.w); fv[7] = u2f_hi(q.w);
      } else {
        const float* fp = (const float*)feat + (size_t)n * DIM + c * 8;
        float4 f0 = *(const float4*)fp;
        float4 f1 = *(const float4*)(fp + 4);
        fv[0] = f0.x; fv[1] = f0.y; fv[2] = f0.z; fv[3] = f0.w;
        fv[4] = f1.x; fv[5] = f1.y; fv[6] = f1.z; fv[7] = f1.w;
      }
      d = 0.f;
#pragma unroll
      for (int j = 0; j < 8; ++j) d += fv[j] * w2r[j];
    } else {
      d = -1.0e30f;                                // poison: slot inactive
#pragma unroll
      for (int j = 0; j < 8; ++j) fv[j] = 0.f;
    }
#pragma unroll
    for (int o = 1; o < 16; o <<= 1) d += __shfl_xor(d, o, 64);
    float m4 = fmaxf(d, __shfl_xor(d, 16, 64));
    m4 = fmaxf(m4, __shfl_xor(m4, 32, 64));
    float mnew = fmaxf(mrun, m4);
    float sc = __expf(mrun - mnew);
    float w = __expf(d - mnew);
    lsum = lsum * sc + w;
#pragma unroll
    for (int j = 0; j < 8; ++j) racc[j] = racc[j] * sc + w * fv[j];
    mrun = mnew;
  }
  float lt = lsum + __shfl_xor(lsum, 16, 64);
  lt += __shfl_xor(lt, 32, 64);
#pragma unroll
  for (int j = 0; j < 8; ++j) {
    racc[j] += __shfl_xor(racc[j], 16, 64);
    racc[j] += __shfl_xor(racc[j], 32, 64);
  }
  if (lid == 0) s_m[wid] = mrun;
  __syncthreads();
  float gmax = fmaxf(fmaxf(s_m[0], s_m[1]), fmaxf(s_m[2], s_m[3]));
  float scw = __expf(mrun - gmax);                 // wave-uniform
  if (lid < 16) {
    float4 lo = make_float4(racc[0] * scw, racc[1] * scw, racc[2] * scw, racc[3] * scw);
    float4 hi = make_float4(racc[4] * scw, racc[5] * scw, racc[6] * scw, racc[7] * scw);
    *(f32x4*)&s_s[wid][c * 8] = *(f32x4*)&lo;
    *(f32x4*)&s_s[wid][c * 8 + 4] = *(f32x4*)&hi;
  }
  if (lid == 0) s_l[wid] = lt * scw;
  __syncthreads();
  float total = s_l[0] + s_l[1] + s_l[2] + s_l[3];
  float inv = 1.f / (total + 1e-7f);
  if (!fin) {
    if (t == 0) g_tp[g] = total * inv;
    if (t < 64) {
      int d0 = t * 2;
      float v0 = (s_s[0][d0] + s_s[1][d0] + s_s[2][d0] + s_s[3][d0]) * inv;
      float v1 = (s_s[0][d0 + 1] + s_s[1][d0 + 1] + s_s[2][d0 + 1] + s_s[3][d0 + 1]) * inv;
      ((unsigned*)g_Acat)[(size_t)g * 320 + 256 + t] =
          (unsigned)f2h(v0) | ((unsigned)f2h(v1) << 16);
    }
  } else {
    if (t == 0) s_tpv[0] = total * inv;
    if (t < 64) {
      int d0 = t * 2;
      s_keep[d0]     = (s_s[0][d0] + s_s[1][d0] + s_s[2][d0] + s_s[3][d0]) * inv;
      s_keep[d0 + 1] = (s_s[0][d0 + 1] + s_s[1][d0 + 1] + s_s[2][d0 + 1] + s_s[3][d0 + 1]) * inv;
    }
    __syncthreads();
    const int jj = t * 2;                          // 512 out cols / 256 threads
    float a0 = 0.f, a1 = 0.f;
    for (int db = 0; db < 16; ++db) {
      half8 w0 = *(const half8*)(g_wm + (size_t)jj * 128 + db * 8);
      half8 w1 = *(const half8*)(g_wm + (size_t)(jj + 1) * 128 + db * 8);
#pragma unroll
      for (int d = 0; d < 8; ++d) {
        float kv = s_keep[db * 8 + d];
        a0 += kv * (float)w0[d];
        a1 += kv * (float)w1[d];
      }
    }
    float tp = s_tpv[0];
    float r0 = a0 + tp * rdf(bm, jj);
    float r1 = a1 + tp * rdf(bm, jj + 1);
    if (israw) {
      ((unsigned*)out)[((size_t)g * 1024 + 512 + jj) >> 1] =
          (unsigned)f2bf(r0) | ((unsigned)f2bf(r1) << 16);
    } else {
      *(float2*)((float*)out + (size_t)g * 1024 + 512 + jj) = make_float2(r0, r1);
    }
  }
}

extern "C" void kernel_launch(void* const* d_in, const int* in_sizes, int n_in,
                              void* d_out, int out_size, void* d_ws, size_t ws_size,
                              hipStream_t stream) {
  const void* features = d_in[0];
  const void* gidx     = d_in[1];
  const void* W_m      = d_in[2];
  const void* b_m      = d_in[3];
  const void* W_ih     = d_in[4];
  const void* W_hh     = d_in[5];
  const void* b_ih     = d_in[6];
  const void* b_hh     = d_in[7];

  k_detect<<<1, 256, 0, stream>>>(features, gidx);
  k_s0<<<1024, 256, 0, stream>>>(gidx, W_m, W_ih, W_hh);
  k_s1<<<193, 256, 0, stream>>>(b_ih, b_hh, b_m);
  // iter 1 attention (h1 graph-independent, w2 = w20)
  k_attn<<<NG, 256, 0, stream>>>(features, 0, 0, 0, d_out, b_m);
  // iter 2: gates = gh + bc + t'*bf + S'@Wfold^T (K=128) -> h2 in Acat
  k_gemm<<<1024, 256, 0, stream>>>(1, 512, 1, 1, 0, 0, d_out);
  k_attn<<<NG, 256, 0, stream>>>(features, 1, 0, 0, d_out, b_m);
  // iter 3: full K=640 gates GEMM -> h3 (separate buffer) + h-half of out
  k_gemm<<<1024, 256, 0, stream>>>(5, 0, 0, 0, 1, 1, d_out);
  // iter 3 attention + r epilogue -> out cols 512..1023
  k_attn<<<NG, 256, 0, stream>>>(features, 1, 1, 1, d_out, b_m);
}

// Round 10
// 224.266 us; speedup vs baseline: 1.6160x; 1.6160x over previous
//
#include <hip/hip_runtime.h>

// ---- problem dims (fixed by setup_inputs) ----
#define N_NODES 131072
#define DIM     128
#define NG      2048
#define HD      512

typedef unsigned short u16;
typedef _Float16 half8 __attribute__((ext_vector_type(8)));
typedef float  f32x4  __attribute__((ext_vector_type(4)));

// ---- static device scratch (referenced ONLY from device code) ----
__device__ u16   g_wm[(size_t)HD * DIM];          // W_m fp16 (rows j, cols d)
__device__ u16   g_wmT[(size_t)DIM * HD];         // W_m^T fp16 (rows d, cols j)
__device__ u16   g_wgf[(size_t)2048 * 640];       // [perm(Wih1+Whh) | perm(Wfold)] fp16
__device__ u16   g_wih2[(size_t)2048 * 512];      // perm(Wih[:,512:]) fp16
__device__ float g_bc[2048];                      // perm(b_ih+b_hh) fp32
__device__ float g_bf[2048];                      // perm(Wih2 @ b_m) fp32
__device__ float g_gh[2048];                      // perm((Wih1+Whh) @ h1) fp32
__device__ float g_c0[512];                       // c1 (graph-independent) fp32
__device__ float g_w20[128];                      // w2_1 = h1 @ W_m fp32
__device__ float g_tp[NG];                        // t' = sum a_n
__device__ u16   g_Acat[(size_t)NG * 640];        // [h2(512) | S'(128)] fp16
__device__ u16   g_h3[(size_t)NG * HD];           // h3 fp16 (separate buffer)
__device__ float g_c[(size_t)NG * HD];
__device__ int   g_start[NG + 1];
__device__ int   g_isbf16;
__device__ int   g_idx64;

__device__ __forceinline__ float bf2f(u16 u) {
  unsigned v = ((unsigned)u) << 16;
  float f; __builtin_memcpy(&f, &v, 4); return f;
}
__device__ __forceinline__ float u2f_hi(unsigned u) {
  unsigned v = u & 0xFFFF0000u;
  float f; __builtin_memcpy(&f, &v, 4); return f;
}
__device__ __forceinline__ float u2f_lo(unsigned u) {
  unsigned v = u << 16;
  float f; __builtin_memcpy(&f, &v, 4); return f;
}
__device__ __forceinline__ u16 f2bf(float f) {
  unsigned u; __builtin_memcpy(&u, &f, 4);
  u += 0x7FFFu + ((u >> 16) & 1u);
  return (u16)(u >> 16);
}
__device__ __forceinline__ u16 f2h(float f) {
  _Float16 h = (_Float16)f; u16 u; __builtin_memcpy(&u, &h, 2); return u;
}
__device__ __forceinline__ float h2f(u16 u) {
  _Float16 h; __builtin_memcpy(&h, &u, 2); return (float)h;
}
__device__ __forceinline__ float rdf(const void* p, int i) {
  return g_isbf16 ? bf2f(((const u16*)p)[i]) : ((const float*)p)[i];
}

#define GLD16(gp, lp) __builtin_amdgcn_global_load_lds(                          \
    (const __attribute__((address_space(1))) void*)(gp),                         \
    (__attribute__((address_space(3))) void*)(lp), 16, 0, 0)

// ---- dtype detection ----
__global__ void k_detect(const void* feat, const void* gi) {
  __shared__ int cnt;
  if (threadIdx.x == 0) cnt = 0;
  __syncthreads();
  u16 u = ((const u16*)feat)[threadIdx.x];
  float v = bf2f(u);
  float a = fabsf(v);
  int ok = (v == v) && a >= 1e-6f && a <= 1e6f;
  atomicAdd(&cnt, ok);
  __syncthreads();
  if (threadIdx.x == 0) {
    g_isbf16 = (cnt >= 230);
    g_idx64 = (((const int*)gi)[N_NODES - 1] == 0);
  }
}

// ---- pair counts. gate-row permutation: permuted row n = 4*j + q ----
#define NWP ((size_t)HD * DIM / 2)
#define NWT ((size_t)DIM * HD / 2)
#define NW1 ((size_t)2048 * 512 / 2)
#define NW2 ((size_t)2048 * 512 / 2)
#define W_PAIRS (NWP + NWT + NW1 + NW2)

// ---- S0: weight conversions (grid-stride) + per-graph start offsets ----
__global__ __launch_bounds__(256) void k_s0(const void* gidxv, const void* wmp,
                                            const void* wih, const void* whh) {
  const int t = threadIdx.x;
  for (size_t i = (size_t)blockIdx.x * 256 + t; i < W_PAIRS;
       i += (size_t)gridDim.x * 256) {
    if (i < NWP) {
      float v0, v1;
      if (g_isbf16) {
        unsigned pr = ((const unsigned*)wmp)[i];
        v0 = bf2f((u16)pr); v1 = bf2f((u16)(pr >> 16));
      } else {
        float2 v = ((const float2*)wmp)[i];
        v0 = v.x; v1 = v.y;
      }
      ((unsigned*)g_wm)[i] = (unsigned)f2h(v0) | ((unsigned)f2h(v1) << 16);
    } else if (i < NWP + NWT) {
      size_t p = i - NWP;
      int d = (int)(p >> 8), j = (int)(p & 255) * 2;
      float v0 = rdf(wmp, j * DIM + d);
      float v1 = rdf(wmp, (j + 1) * DIM + d);
      ((unsigned*)g_wmT)[(size_t)d * 256 + (j >> 1)] =
          (unsigned)f2h(v0) | ((unsigned)f2h(v1) << 16);
    } else if (i < NWP + NWT + NW1) {
      size_t p = i - NWP - NWT;
      int n = (int)(p >> 8), kp = (int)(p & 255), k = kp * 2;
      int orig = (n & 3) * 512 + (n >> 2);
      float v0 = rdf(wih, orig * 1024 + k)     + rdf(whh, orig * 512 + k);
      float v1 = rdf(wih, orig * 1024 + k + 1) + rdf(whh, orig * 512 + k + 1);
      ((unsigned*)g_wgf)[(size_t)n * 320 + kp] =
          (unsigned)f2h(v0) | ((unsigned)f2h(v1) << 16);
    } else {
      size_t p = i - NWP - NWT - NW1;
      int n = (int)(p >> 8), kp = (int)(p & 255), k = kp * 2;
      int orig = (n & 3) * 512 + (n >> 2);
      float v0 = rdf(wih, orig * 1024 + 512 + k);
      float v1 = rdf(wih, orig * 1024 + 512 + k + 1);
      ((unsigned*)g_wih2)[(size_t)n * 256 + kp] =
          (unsigned)f2h(v0) | ((unsigned)f2h(v1) << 16);
    }
  }
  if (blockIdx.x < 512) {
    int n = blockIdx.x * 256 + t;
    const int idx64 = g_idx64;
    int gg = idx64 ? (int)((const long long*)gidxv)[n] : ((const int*)gidxv)[n];
    if (n == 0) {
      for (int x = 0; x <= gg; ++x) g_start[x] = 0;
    } else {
      int gp = idx64 ? (int)((const long long*)gidxv)[n - 1] : ((const int*)gidxv)[n - 1];
      for (int x = gp + 1; x <= gg; ++x) g_start[x] = n;
    }
    if (n == N_NODES - 1) {
      for (int x = gg + 1; x <= NG; ++x) g_start[x] = N_NODES;
    }
  }
}

// ---- S1: bc/bf/gh vectors (blocks 0..127), Wfold GEMM (128..191), c0/w20 (192) ----
__global__ __launch_bounds__(256) void k_s1(const void* bih, const void* bhh,
                                            const void* bm) {
  alignas(16) __shared__ char smem[16384];
  const int t = threadIdx.x, b = blockIdx.x;
  if (b < 128) {
    float* s_bm = (float*)smem;                    // [512]
    float* s_h0 = s_bm + 512;                      // [512]
    for (int p = t; p < 512; p += 256) {
      s_bm[p] = rdf(bm, p);
      float xi = rdf(bih, p)        + rdf(bhh, p);
      float xg = rdf(bih, p + 1024) + rdf(bhh, p + 1024);
      float xo = rdf(bih, p + 1536) + rdf(bhh, p + 1536);
      float si = 1.f / (1.f + __expf(-xi));
      float tg = tanhf(xg);
      float so = 1.f / (1.f + __expf(-xo));
      s_h0[p] = so * tanhf(si * tg);
    }
    __syncthreads();
    const int rloc = t >> 4, k = t & 15;           // 16 rows/block, 16 lanes/row
    const int n = b * 16 + rloc;
    float sbf = 0.f, sgh = 0.f;
#pragma unroll
    for (int j = 0; j < 4; ++j) {
      const int e = k * 8 + j * 128;
      half8 w2v = *(const half8*)(g_wih2 + (size_t)n * 512 + e);
      half8 w1v = *(const half8*)(g_wgf  + (size_t)n * 640 + e);
#pragma unroll
      for (int d = 0; d < 8; ++d) {
        sbf += (float)w2v[d] * s_bm[e + d];
        sgh += (float)w1v[d] * s_h0[e + d];
      }
    }
#pragma unroll
    for (int o = 1; o < 16; o <<= 1) {
      sbf += __shfl_xor(sbf, o, 64);
      sgh += __shfl_xor(sgh, o, 64);
    }
    if (k == 0) {
      const int orig = (n & 3) * 512 + (n >> 2);
      g_bf[n] = sbf;
      g_gh[n] = sgh;
      g_bc[n] = rdf(bih, orig) + rdf(bhh, orig);
    }
  } else if (b < 192) {
    u16* As = (u16*)smem;                          // [64*64]
    u16* Bs = As + 4096;
    const int bx = b - 128;
    const int lid = t & 63, w = t >> 6;
    const int m0 = (bx & 31) * 64, n0 = (bx >> 5) * 64;
    const int rr = lid & 15, quad = lid >> 4;
    const int rsub = lid >> 3;
    const int cs = (lid & 7) ^ rsub;
    const int wm = (w >> 1) * 32, wn = (w & 1) * 32;
    f32x4 acc[2][2] = {};
    for (int kt = 0; kt < 8; ++kt) {
      const int k0 = kt * 64;
      GLD16(g_wih2 + (size_t)(m0 + w * 16 + rsub) * 512 + k0 + cs * 8, As + (w * 16) * 64);
      GLD16(g_wih2 + (size_t)(m0 + w * 16 + 8 + rsub) * 512 + k0 + cs * 8, As + (w * 16 + 8) * 64);
      GLD16(g_wmT + (size_t)(n0 + w * 16 + rsub) * 512 + k0 + cs * 8, Bs + (w * 16) * 64);
      GLD16(g_wmT + (size_t)(n0 + w * 16 + 8 + rsub) * 512 + k0 + cs * 8, Bs + (w * 16 + 8) * 64);
      __syncthreads();
#pragma unroll
      for (int kk = 0; kk < 2; ++kk) {
        const int qb = kk * 4 + quad;
        const int sw = (qb ^ (rr & 7)) << 3;
        half8 af[2], bfr[2];
#pragma unroll
        for (int i = 0; i < 2; ++i) af[i]  = *(const half8*)(As + (wm + i * 16 + rr) * 64 + sw);
#pragma unroll
        for (int j = 0; j < 2; ++j) bfr[j] = *(const half8*)(Bs + (wn + j * 16 + rr) * 64 + sw);
#pragma unroll
        for (int i = 0; i < 2; ++i)
#pragma unroll
          for (int j = 0; j < 2; ++j)
            acc[i][j] = __builtin_amdgcn_mfma_f32_16x16x32_f16(bfr[j], af[i], acc[i][j], 0, 0, 0);
      }
      __syncthreads();
    }
#pragma unroll
    for (int i = 0; i < 2; ++i)
#pragma unroll
      for (int j = 0; j < 2; ++j) {
        const int row = m0 + wm + i * 16 + rr;
        const int c0 = n0 + wn + j * 16 + quad * 4;
        u16 h4[4];
#pragma unroll
        for (int r = 0; r < 4; ++r) h4[r] = f2h(acc[i][j][r]);
        *(uint2*)(g_wgf + (size_t)row * 640 + 512 + c0) =
            make_uint2((unsigned)h4[0] | ((unsigned)h4[1] << 16),
                       (unsigned)h4[2] | ((unsigned)h4[3] << 16));
      }
  } else if (b == 192) {
    float* s_h   = (float*)smem;                   // [512]
    float* s_red = s_h + 512;                      // [4][128]
    for (int j = t; j < 512; j += 256) {
      float xi = rdf(bih, j)        + rdf(bhh, j);
      float xg = rdf(bih, j + 1024) + rdf(bhh, j + 1024);
      float xo = rdf(bih, j + 1536) + rdf(bhh, j + 1536);
      float si = 1.f / (1.f + __expf(-xi));
      float tg = tanhf(xg);
      float so = 1.f / (1.f + __expf(-xo));
      float cn = si * tg;
      float hn = so * tanhf(cn);
      g_c0[j] = cn;
      s_h[j] = hn;
    }
    __syncthreads();
    const int dg = t & 15, jg = t >> 4;
    float a8[8] = {};
    for (int jj = 0; jj < 32; ++jj) {
      const int j = jg * 32 + jj;
      half8 wv = *(const half8*)(g_wm + (size_t)j * 128 + dg * 8);
      const float hv = s_h[j];
#pragma unroll
      for (int d = 0; d < 8; ++d) a8[d] += hv * (float)wv[d];
    }
#pragma unroll
    for (int d = 0; d < 8; ++d) {
      a8[d] += __shfl_xor(a8[d], 16, 64);
      a8[d] += __shfl_xor(a8[d], 32, 64);
    }
    const int w = t >> 6;
    if ((t & 63) < 16) {
      *(f32x4*)&s_red[w * 128 + dg * 8]     = *(f32x4*)&a8[0];
      *(f32x4*)&s_red[w * 128 + dg * 8 + 4] = *(f32x4*)&a8[4];
    }
    __syncthreads();
    if (t < 128)
      g_w20[t] = s_red[t] + s_red[128 + t] + s_red[256 + t] + s_red[384 + t];
  }
}

// ---- gates GEMM (one 64x64 tile per block) + fused LSTM epilogue.
// h3out=0: new h -> g_Acat h-half (A-reads touch only S' cols, aoff=512).
// h3out=1: new h -> g_h3 (A-reads cover h cols; separate buffer, no race). ----
__global__ __launch_bounds__(256) void k_gemm(int ktiles2, int aoff, int useGh,
                                              int first, int wout, int h3out,
                                              void* __restrict__ out) {
  alignas(16) __shared__ u16 As[2][64 * 64];
  alignas(16) __shared__ u16 Bs[2][64 * 64];
  const int t = threadIdx.x, lid = t & 63, w = t >> 6;
  const int m0 = (blockIdx.x & 31) * 64, n0 = (blockIdx.x >> 5) * 64;
  const int rr = lid & 15, quad = lid >> 4;
  const int rsub = lid >> 3;
  const int cs = (lid & 7) ^ rsub;
  const int wm = (w >> 1) * 32, wn = (w & 1) * 32;
  const int isb = g_isbf16;
  f32x4 acc[2][2] = {};
  for (int kt2 = 0; kt2 < ktiles2; ++kt2) {
#pragma unroll
    for (int b = 0; b < 2; ++b) {
      const int k0 = aoff + (kt2 * 2 + b) * 64;
      GLD16(g_Acat + (size_t)(m0 + w * 16 + rsub) * 640 + k0 + cs * 8, As[b] + (w * 16) * 64);
      GLD16(g_Acat + (size_t)(m0 + w * 16 + 8 + rsub) * 640 + k0 + cs * 8, As[b] + (w * 16 + 8) * 64);
      GLD16(g_wgf  + (size_t)(n0 + w * 16 + rsub) * 640 + k0 + cs * 8, Bs[b] + (w * 16) * 64);
      GLD16(g_wgf  + (size_t)(n0 + w * 16 + 8 + rsub) * 640 + k0 + cs * 8, Bs[b] + (w * 16 + 8) * 64);
    }
    __syncthreads();
#pragma unroll
    for (int b = 0; b < 2; ++b)
#pragma unroll
      for (int kk = 0; kk < 2; ++kk) {
        const int qb = kk * 4 + quad;
        const int sw = (qb ^ (rr & 7)) << 3;
        half8 af[2], bfr[2];
#pragma unroll
        for (int i = 0; i < 2; ++i) af[i]  = *(const half8*)(As[b] + (wm + i * 16 + rr) * 64 + sw);
#pragma unroll
        for (int j = 0; j < 2; ++j) bfr[j] = *(const half8*)(Bs[b] + (wn + j * 16 + rr) * 64 + sw);
#pragma unroll
        for (int i = 0; i < 2; ++i)
#pragma unroll
          for (int j = 0; j < 2; ++j)
            acc[i][j] = __builtin_amdgcn_mfma_f32_16x16x32_f16(bfr[j], af[i], acc[i][j], 0, 0, 0);
      }
    __syncthreads();
  }
#pragma unroll
  for (int i = 0; i < 2; ++i) {
    const int row = m0 + wm + i * 16 + rr;           // graph
    const float tp = g_tp[row];
#pragma unroll
    for (int j = 0; j < 2; ++j) {
      const int c0 = n0 + wn + j * 16 + quad * 4;    // permuted gate col, %4==0
      const int jj = c0 >> 2;                        // hidden index
      float4 bc = *(const float4*)(g_bc + c0);
      float4 bf = *(const float4*)(g_bf + c0);
      float gx = 0.f, gy = 0.f, gz = 0.f, gw = 0.f;
      if (useGh) {
        float4 gh = *(const float4*)(g_gh + c0);
        gx = gh.x; gy = gh.y; gz = gh.z; gw = gh.w;
      }
      float xi = acc[i][j][0] + bc.x + gx + tp * bf.x;
      float xf = acc[i][j][1] + bc.y + gy + tp * bf.y;
      float xg = acc[i][j][2] + bc.z + gz + tp * bf.z;
      float xo = acc[i][j][3] + bc.w + gw + tp * bf.w;
      float si = 1.f / (1.f + __expf(-xi));
      float sf = 1.f / (1.f + __expf(-xf));
      float tg = tanhf(xg);
      float so = 1.f / (1.f + __expf(-xo));
      float cp = first ? g_c0[jj] : g_c[(size_t)row * 512 + jj];
      float cn = sf * cp + si * tg;
      float hn = so * tanhf(cn);
      g_c[(size_t)row * 512 + jj] = cn;
      if (h3out) g_h3[(size_t)row * 512 + jj] = f2h(hn);
      else       g_Acat[(size_t)row * 640 + jj] = f2h(hn);
      if (wout) {
        if (isb) ((u16*)out)[(size_t)row * 1024 + jj] = f2bf(hn);
        else     ((float*)out)[(size_t)row * 1024 + jj] = hn;
      }
    }
  }
}

// ---- attention: one graph per block.
// mode 0: w2 = g_w20. mode 1: w2 = h[g] @ W_m in-block.
// hsel: 0 -> h from g_Acat (stride 640); 1 -> h from g_h3 (stride 512).
// fin=0: S' fp16 -> Acat, t' -> g_tp. fin=1: r = S'@W_m^T + t'*b_m -> out,
// computed from g_wmT with coalesced per-d u32 reads (lane t -> cols 2t,2t+1). ----
__global__ __launch_bounds__(256) void k_attn(const void* __restrict__ feat, int mode,
                                              int hsel, int fin,
                                              void* __restrict__ out,
                                              const void* __restrict__ bm) {
  __shared__ float s_m[4], s_l[4];
  __shared__ float s_s[4][DIM];
  __shared__ float s_h[512];
  __shared__ float s_keep[DIM];
  __shared__ float s_tpv[1];
  const int g = blockIdx.x;
  const int t = threadIdx.x, lid = t & 63, wid = t >> 6;
  const int c = lid & 15;                          // 8-col chunk index
  const int slot = lid >> 4;                       // node slot 0..3
  const int israw = g_isbf16;
  const int s = g_start[g], e = g_start[g + 1];
  float w2r[8];
  if (mode) {
    const u16* hsrc = hsel ? g_h3 : g_Acat;        // device-resolved symbols
    const int hstr = hsel ? 512 : 640;
    for (int p = t; p < 512; p += 256)
      s_h[p] = h2f(hsrc[(size_t)g * hstr + p]);
    __syncthreads();
    const int jg = t >> 4;
    float a8[8] = {};
    for (int jj = 0; jj < 32; ++jj) {
      const int j = jg * 32 + jj;
      half8 wv = *(const half8*)(g_wm + (size_t)j * 128 + c * 8);
      const float hv = s_h[j];
#pragma unroll
      for (int d = 0; d < 8; ++d) a8[d] += hv * (float)wv[d];
    }
#pragma unroll
    for (int d = 0; d < 8; ++d) {
      a8[d] += __shfl_xor(a8[d], 16, 64);
      a8[d] += __shfl_xor(a8[d], 32, 64);
    }
    if (lid < 16) {
      *(f32x4*)&s_s[wid][c * 8]     = *(f32x4*)&a8[0];
      *(f32x4*)&s_s[wid][c * 8 + 4] = *(f32x4*)&a8[4];
    }
    __syncthreads();
#pragma unroll
    for (int d = 0; d < 8; ++d)
      w2r[d] = s_s[0][c * 8 + d] + s_s[1][c * 8 + d] +
               s_s[2][c * 8 + d] + s_s[3][c * 8 + d];
    __syncthreads();                               // s_s reused below
  } else {
    *(float4*)(w2r)     = *(const float4*)(g_w20 + c * 8);
    *(float4*)(w2r + 4) = *(const float4*)(g_w20 + c * 8 + 4);
  }
  float mrun = -3.0e38f, lsum = 0.f;
  float racc[8] = {0.f, 0.f, 0.f, 0.f, 0.f, 0.f, 0.f, 0.f};
  for (int nb = s + wid * 4; nb < e; nb += 16) {   // 4 waves x 4 slots
    const int n = nb + slot;
    float fv[8], d;
    if (n < e) {
      if (israw) {
        uint4 q = *(const uint4*)((const u16*)feat + (size_t)n * DIM + c * 8);
        fv[0] = u2f_lo(q.x); fv[1] = u2f_hi(q.x);
        fv[2] = u2f_lo(q.y); fv[3] = u2f_hi(q.y);
        fv[4] = u2f_lo(q.z); fv[5] = u2f_hi(q.z);
        fv[6] = u2f_lo(q.w); fv[7] = u2f_hi(q.w);
      } else {
        const float* fp = (const float*)feat + (size_t)n * DIM + c * 8;
        float4 f0 = *(const float4*)fp;
        float4 f1 = *(const float4*)(fp + 4);
        fv[0] = f0.x; fv[1] = f0.y; fv[2] = f0.z; fv[3] = f0.w;
        fv[4] = f1.x; fv[5] = f1.y; fv[6] = f1.z; fv[7] = f1.w;
      }
      d = 0.f;
#pragma unroll
      for (int j = 0; j < 8; ++j) d += fv[j] * w2r[j];
    } else {
      d = -1.0e30f;                                // poison: slot inactive
#pragma unroll
      for (int j = 0; j < 8; ++j) fv[j] = 0.f;
    }
#pragma unroll
    for (int o = 1; o < 16; o <<= 1) d += __shfl_xor(d, o, 64);
    float m4 = fmaxf(d, __shfl_xor(d, 16, 64));
    m4 = fmaxf(m4, __shfl_xor(m4, 32, 64));
    float mnew = fmaxf(mrun, m4);
    float sc = __expf(mrun - mnew);
    float w = __expf(d - mnew);
    lsum = lsum * sc + w;
#pragma unroll
    for (int j = 0; j < 8; ++j) racc[j] = racc[j] * sc + w * fv[j];
    mrun = mnew;
  }
  float lt = lsum + __shfl_xor(lsum, 16, 64);
  lt += __shfl_xor(lt, 32, 64);
#pragma unroll
  for (int j = 0; j < 8; ++j) {
    racc[j] += __shfl_xor(racc[j], 16, 64);
    racc[j] += __shfl_xor(racc[j], 32, 64);
  }
  if (lid == 0) s_m[wid] = mrun;
  __syncthreads();
  float gmax = fmaxf(fmaxf(s_m[0], s_m[1]), fmaxf(s_m[2], s_m[3]));
  float scw = __expf(mrun - gmax);                 // wave-uniform
  if (lid < 16) {
    float4 lo = make_float4(racc[0] * scw, racc[1] * scw, racc[2] * scw, racc[3] * scw);
    float4 hi = make_float4(racc[4] * scw, racc[5] * scw, racc[6] * scw, racc[7] * scw);
    *(f32x4*)&s_s[wid][c * 8] = *(f32x4*)&lo;
    *(f32x4*)&s_s[wid][c * 8 + 4] = *(f32x4*)&hi;
  }
  if (lid == 0) s_l[wid] = lt * scw;
  __syncthreads();
  float total = s_l[0] + s_l[1] + s_l[2] + s_l[3];
  float inv = 1.f / (total + 1e-7f);
  if (!fin) {
    if (t == 0) g_tp[g] = total * inv;
    if (t < 64) {
      int d0 = t * 2;
      float v0 = (s_s[0][d0] + s_s[1][d0] + s_s[2][d0] + s_s[3][d0]) * inv;
      float v1 = (s_s[0][d0 + 1] + s_s[1][d0 + 1] + s_s[2][d0 + 1] + s_s[3][d0 + 1]) * inv;
      ((unsigned*)g_Acat)[(size_t)g * 320 + 256 + t] =
          (unsigned)f2h(v0) | ((unsigned)f2h(v1) << 16);
    }
  } else {
    if (t == 0) s_tpv[0] = total * inv;
    if (t < 64) {
      int d0 = t * 2;
      s_keep[d0]     = (s_s[0][d0] + s_s[1][d0] + s_s[2][d0] + s_s[3][d0]) * inv;
      s_keep[d0 + 1] = (s_s[0][d0 + 1] + s_s[1][d0 + 1] + s_s[2][d0 + 1] + s_s[3][d0 + 1]) * inv;
    }
    __syncthreads();
    // r[2t], r[2t+1] from g_wmT: lane t reads u32 at [d*256 + t] -> cols 2t,2t+1
    // of row d. Lanes consecutive -> 256 B coalesced per d (vs 512B-stride
    // per-lane g_wm walk that was 64x16B scattered requests = the 120 us).
    const int jj = t * 2;
    const unsigned* wt = (const unsigned*)g_wmT;
    float a0 = 0.f, a1 = 0.f;
#pragma unroll 8
    for (int d = 0; d < 128; ++d) {
      unsigned pr = wt[d * 256 + t];
      float kv = s_keep[d];
      a0 += kv * h2f((u16)pr);
      a1 += kv * h2f((u16)(pr >> 16));
    }
    float tp = s_tpv[0];
    float r0 = a0 + tp * rdf(bm, jj);
    float r1 = a1 + tp * rdf(bm, jj + 1);
    if (israw) {
      ((unsigned*)out)[((size_t)g * 1024 + 512 + jj) >> 1] =
          (unsigned)f2bf(r0) | ((unsigned)f2bf(r1) << 16);
    } else {
      *(float2*)((float*)out + (size_t)g * 1024 + 512 + jj) = make_float2(r0, r1);
    }
  }
}

extern "C" void kernel_launch(void* const* d_in, const int* in_sizes, int n_in,
                              void* d_out, int out_size, void* d_ws, size_t ws_size,
                              hipStream_t stream) {
  const void* features = d_in[0];
  const void* gidx     = d_in[1];
  const void* W_m      = d_in[2];
  const void* b_m      = d_in[3];
  const void* W_ih     = d_in[4];
  const void* W_hh     = d_in[5];
  const void* b_ih     = d_in[6];
  const void* b_hh     = d_in[7];

  k_detect<<<1, 256, 0, stream>>>(features, gidx);
  k_s0<<<1024, 256, 0, stream>>>(gidx, W_m, W_ih, W_hh);
  k_s1<<<193, 256, 0, stream>>>(b_ih, b_hh, b_m);
  // iter 1 attention (h1 graph-independent, w2 = w20)
  k_attn<<<NG, 256, 0, stream>>>(features, 0, 0, 0, d_out, b_m);
  // iter 2: gates = gh + bc + t'*bf + S'@Wfold^T (K=128) -> h2 in Acat
  k_gemm<<<1024, 256, 0, stream>>>(1, 512, 1, 1, 0, 0, d_out);
  k_attn<<<NG, 256, 0, stream>>>(features, 1, 0, 0, d_out, b_m);
  // iter 3: full K=640 gates GEMM -> h3 (separate buffer) + h-half of out
  k_gemm<<<1024, 256, 0, stream>>>(5, 0, 0, 0, 1, 1, d_out);
  // iter 3 attention + r epilogue -> out cols 512..1023
  k_attn<<<NG, 256, 0, stream>>>(features, 1, 1, 1, d_out, b_m);
}

// Round 12
// 211.380 us; speedup vs baseline: 1.7146x; 1.0610x over previous
//
#include <hip/hip_runtime.h>

// ---- problem dims (fixed by setup_inputs) ----
#define N_NODES 131072
#define DIM     128
#define NG      2048
#define HD      512

typedef unsigned short u16;
typedef _Float16 half8 __attribute__((ext_vector_type(8)));
typedef float  f32x4  __attribute__((ext_vector_type(4)));

// ---- static device scratch (referenced ONLY from device code) ----
__device__ u16   g_wm[(size_t)HD * DIM];          // W_m fp16 (rows j, cols d)
__device__ u16   g_wmT[(size_t)DIM * HD];         // W_m^T fp16 (rows d, cols j)
__device__ u16   g_wgf[(size_t)2048 * 640];       // [perm(Wih1+Whh) | perm(Wfold)] fp16
__device__ u16   g_wih2[(size_t)2048 * 512];      // perm(Wih[:,512:]) fp16
__device__ float g_bc[2048];                      // perm(b_ih+b_hh) fp32
__device__ float g_bf[2048];                      // perm(Wih2 @ b_m) fp32
__device__ float g_gh[2048];                      // perm((Wih1+Whh) @ h1) fp32
__device__ float g_c0[512];                       // c1 (graph-independent) fp32
__device__ float g_w20[128];                      // w2_1 = h1 @ W_m fp32
__device__ float g_w2[(size_t)NG * DIM];          // per-graph w2 = h @ W_m fp32
__device__ float g_tp[NG];                        // t' = sum a_n
__device__ u16   g_Acat[(size_t)NG * 640];        // [h2(512) | S'(128)] fp16
__device__ u16   g_h3[(size_t)NG * HD];           // h3 fp16 (separate buffer)
__device__ float g_c[(size_t)NG * HD];
__device__ int   g_start[NG + 1];
__device__ int   g_isbf16;
__device__ int   g_idx64;

__device__ __forceinline__ float bf2f(u16 u) {
  unsigned v = ((unsigned)u) << 16;
  float f; __builtin_memcpy(&f, &v, 4); return f;
}
__device__ __forceinline__ float u2f_hi(unsigned u) {
  unsigned v = u & 0xFFFF0000u;
  float f; __builtin_memcpy(&f, &v, 4); return f;
}
__device__ __forceinline__ float u2f_lo(unsigned u) {
  unsigned v = u << 16;
  float f; __builtin_memcpy(&f, &v, 4); return f;
}
__device__ __forceinline__ u16 f2bf(float f) {
  unsigned u; __builtin_memcpy(&u, &f, 4);
  u += 0x7FFFu + ((u >> 16) & 1u);
  return (u16)(u >> 16);
}
__device__ __forceinline__ u16 f2h(float f) {
  _Float16 h = (_Float16)f; u16 u; __builtin_memcpy(&u, &h, 2); return u;
}
__device__ __forceinline__ float h2f(u16 u) {
  _Float16 h; __builtin_memcpy(&h, &u, 2); return (float)h;
}
__device__ __forceinline__ float rdf(const void* p, int i) {
  return g_isbf16 ? bf2f(((const u16*)p)[i]) : ((const float*)p)[i];
}
// local-isb variant for k_s0 (g_isbf16 not yet published)
__device__ __forceinline__ float rdl(const void* p, int i, int isb) {
  return isb ? bf2f(((const u16*)p)[i]) : ((const float*)p)[i];
}

#define GLD16(gp, lp) __builtin_amdgcn_global_load_lds(                          \
    (const __attribute__((address_space(1))) void*)(gp),                         \
    (__attribute__((address_space(3))) void*)(lp), 16, 0, 0)

// ---- pair counts. gate-row permutation: permuted row n = 4*j + q ----
#define NWP ((size_t)HD * DIM / 2)
#define NWT ((size_t)DIM * HD / 2)
#define NW1 ((size_t)2048 * 512 / 2)
#define NW2 ((size_t)2048 * 512 / 2)
#define W_PAIRS (NWP + NWT + NW1 + NW2)

// ---- S0: dtype detect (block-local) + weight conversions + start offsets ----
__global__ __launch_bounds__(256) void k_s0(const void* feat, const void* gidxv,
                                            const void* wmp, const void* wih,
                                            const void* whh) {
  __shared__ int s_cnt;
  const int t = threadIdx.x;
  if (t == 0) s_cnt = 0;
  __syncthreads();
  {
    u16 u = ((const u16*)feat)[t];
    float v = bf2f(u);
    float a = fabsf(v);
    int ok = (v == v) && a >= 1e-6f && a <= 1e6f;
    atomicAdd(&s_cnt, ok);
  }
  __syncthreads();
  const int isb = (s_cnt >= 230);
  const int idx64 = (((const int*)gidxv)[N_NODES - 1] == 0);
  if (blockIdx.x == 0 && t == 0) { g_isbf16 = isb; g_idx64 = idx64; }

  for (size_t i = (size_t)blockIdx.x * 256 + t; i < W_PAIRS;
       i += (size_t)gridDim.x * 256) {
    if (i < NWP) {
      float v0, v1;
      if (isb) {
        unsigned pr = ((const unsigned*)wmp)[i];
        v0 = bf2f((u16)pr); v1 = bf2f((u16)(pr >> 16));
      } else {
        float2 v = ((const float2*)wmp)[i];
        v0 = v.x; v1 = v.y;
      }
      ((unsigned*)g_wm)[i] = (unsigned)f2h(v0) | ((unsigned)f2h(v1) << 16);
    } else if (i < NWP + NWT) {
      size_t p = i - NWP;
      int d = (int)(p >> 8), j = (int)(p & 255) * 2;
      float v0 = rdl(wmp, j * DIM + d, isb);
      float v1 = rdl(wmp, (j + 1) * DIM + d, isb);
      ((unsigned*)g_wmT)[(size_t)d * 256 + (j >> 1)] =
          (unsigned)f2h(v0) | ((unsigned)f2h(v1) << 16);
    } else if (i < NWP + NWT + NW1) {
      size_t p = i - NWP - NWT;
      int n = (int)(p >> 8), kp = (int)(p & 255), k = kp * 2;
      int orig = (n & 3) * 512 + (n >> 2);
      float v0 = rdl(wih, orig * 1024 + k, isb)     + rdl(whh, orig * 512 + k, isb);
      float v1 = rdl(wih, orig * 1024 + k + 1, isb) + rdl(whh, orig * 512 + k + 1, isb);
      ((unsigned*)g_wgf)[(size_t)n * 320 + kp] =
          (unsigned)f2h(v0) | ((unsigned)f2h(v1) << 16);
    } else {
      size_t p = i - NWP - NWT - NW1;
      int n = (int)(p >> 8), kp = (int)(p & 255), k = kp * 2;
      int orig = (n & 3) * 512 + (n >> 2);
      float v0 = rdl(wih, orig * 1024 + 512 + k, isb);
      float v1 = rdl(wih, orig * 1024 + 512 + k + 1, isb);
      ((unsigned*)g_wih2)[(size_t)n * 256 + kp] =
          (unsigned)f2h(v0) | ((unsigned)f2h(v1) << 16);
    }
  }
  if (blockIdx.x < 512) {
    int n = blockIdx.x * 256 + t;
    int gg = idx64 ? (int)((const long long*)gidxv)[n] : ((const int*)gidxv)[n];
    if (n == 0) {
      for (int x = 0; x <= gg; ++x) g_start[x] = 0;
    } else {
      int gp = idx64 ? (int)((const long long*)gidxv)[n - 1] : ((const int*)gidxv)[n - 1];
      for (int x = gp + 1; x <= gg; ++x) g_start[x] = n;
    }
    if (n == N_NODES - 1) {
      for (int x = gg + 1; x <= NG; ++x) g_start[x] = N_NODES;
    }
  }
}

// ---- S1: bc/bf/gh vectors (blocks 0..127), Wfold GEMM (128..191), c0/w20 (192) ----
__global__ __launch_bounds__(256) void k_s1(const void* bih, const void* bhh,
                                            const void* bm) {
  alignas(16) __shared__ char smem[16384];
  const int t = threadIdx.x, b = blockIdx.x;
  if (b < 128) {
    float* s_bm = (float*)smem;                    // [512]
    float* s_h0 = s_bm + 512;                      // [512]
    for (int p = t; p < 512; p += 256) {
      s_bm[p] = rdf(bm, p);
      float xi = rdf(bih, p)        + rdf(bhh, p);
      float xg = rdf(bih, p + 1024) + rdf(bhh, p + 1024);
      float xo = rdf(bih, p + 1536) + rdf(bhh, p + 1536);
      float si = 1.f / (1.f + __expf(-xi));
      float tg = tanhf(xg);
      float so = 1.f / (1.f + __expf(-xo));
      s_h0[p] = so * tanhf(si * tg);
    }
    __syncthreads();
    const int rloc = t >> 4, k = t & 15;           // 16 rows/block, 16 lanes/row
    const int n = b * 16 + rloc;
    float sbf = 0.f, sgh = 0.f;
#pragma unroll
    for (int j = 0; j < 4; ++j) {
      const int e = k * 8 + j * 128;
      half8 w2v = *(const half8*)(g_wih2 + (size_t)n * 512 + e);
      half8 w1v = *(const half8*)(g_wgf  + (size_t)n * 640 + e);
#pragma unroll
      for (int d = 0; d < 8; ++d) {
        sbf += (float)w2v[d] * s_bm[e + d];
        sgh += (float)w1v[d] * s_h0[e + d];
      }
    }
#pragma unroll
    for (int o = 1; o < 16; o <<= 1) {
      sbf += __shfl_xor(sbf, o, 64);
      sgh += __shfl_xor(sgh, o, 64);
    }
    if (k == 0) {
      const int orig = (n & 3) * 512 + (n >> 2);
      g_bf[n] = sbf;
      g_gh[n] = sgh;
      g_bc[n] = rdf(bih, orig) + rdf(bhh, orig);
    }
  } else if (b < 192) {
    u16* As = (u16*)smem;                          // [64*64]
    u16* Bs = As + 4096;
    const int bx = b - 128;
    const int lid = t & 63, w = t >> 6;
    const int m0 = (bx & 31) * 64, n0 = (bx >> 5) * 64;
    const int rr = lid & 15, quad = lid >> 4;
    const int rsub = lid >> 3;
    const int cs = (lid & 7) ^ rsub;
    const int wm = (w >> 1) * 32, wn = (w & 1) * 32;
    f32x4 acc[2][2] = {};
    for (int kt = 0; kt < 8; ++kt) {
      const int k0 = kt * 64;
      GLD16(g_wih2 + (size_t)(m0 + w * 16 + rsub) * 512 + k0 + cs * 8, As + (w * 16) * 64);
      GLD16(g_wih2 + (size_t)(m0 + w * 16 + 8 + rsub) * 512 + k0 + cs * 8, As + (w * 16 + 8) * 64);
      GLD16(g_wmT + (size_t)(n0 + w * 16 + rsub) * 512 + k0 + cs * 8, Bs + (w * 16) * 64);
      GLD16(g_wmT + (size_t)(n0 + w * 16 + 8 + rsub) * 512 + k0 + cs * 8, Bs + (w * 16 + 8) * 64);
      __syncthreads();
#pragma unroll
      for (int kk = 0; kk < 2; ++kk) {
        const int qb = kk * 4 + quad;
        const int sw = (qb ^ (rr & 7)) << 3;
        half8 af[2], bfr[2];
#pragma unroll
        for (int i = 0; i < 2; ++i) af[i]  = *(const half8*)(As + (wm + i * 16 + rr) * 64 + sw);
#pragma unroll
        for (int j = 0; j < 2; ++j) bfr[j] = *(const half8*)(Bs + (wn + j * 16 + rr) * 64 + sw);
#pragma unroll
        for (int i = 0; i < 2; ++i)
#pragma unroll
          for (int j = 0; j < 2; ++j)
            acc[i][j] = __builtin_amdgcn_mfma_f32_16x16x32_f16(bfr[j], af[i], acc[i][j], 0, 0, 0);
      }
      __syncthreads();
    }
#pragma unroll
    for (int i = 0; i < 2; ++i)
#pragma unroll
      for (int j = 0; j < 2; ++j) {
        const int row = m0 + wm + i * 16 + rr;
        const int c0 = n0 + wn + j * 16 + quad * 4;
        u16 h4[4];
#pragma unroll
        for (int r = 0; r < 4; ++r) h4[r] = f2h(acc[i][j][r]);
        *(uint2*)(g_wgf + (size_t)row * 640 + 512 + c0) =
            make_uint2((unsigned)h4[0] | ((unsigned)h4[1] << 16),
                       (unsigned)h4[2] | ((unsigned)h4[3] << 16));
      }
  } else if (b == 192) {
    float* s_h   = (float*)smem;                   // [512]
    float* s_red = s_h + 512;                      // [4][128]
    for (int j = t; j < 512; j += 256) {
      float xi = rdf(bih, j)        + rdf(bhh, j);
      float xg = rdf(bih, j + 1024) + rdf(bhh, j + 1024);
      float xo = rdf(bih, j + 1536) + rdf(bhh, j + 1536);
      float si = 1.f / (1.f + __expf(-xi));
      float tg = tanhf(xg);
      float so = 1.f / (1.f + __expf(-xo));
      float cn = si * tg;
      float hn = so * tanhf(cn);
      g_c0[j] = cn;
      s_h[j] = hn;
    }
    __syncthreads();
    const int dg = t & 15, jg = t >> 4;
    float a8[8] = {};
    for (int jj = 0; jj < 32; ++jj) {
      const int j = jg * 32 + jj;
      half8 wv = *(const half8*)(g_wm + (size_t)j * 128 + dg * 8);
      const float hv = s_h[j];
#pragma unroll
      for (int d = 0; d < 8; ++d) a8[d] += hv * (float)wv[d];
    }
#pragma unroll
    for (int d = 0; d < 8; ++d) {
      a8[d] += __shfl_xor(a8[d], 16, 64);
      a8[d] += __shfl_xor(a8[d], 32, 64);
    }
    const int w = t >> 6;
    if ((t & 63) < 16) {
      *(f32x4*)&s_red[w * 128 + dg * 8]     = *(f32x4*)&a8[0];
      *(f32x4*)&s_red[w * 128 + dg * 8 + 4] = *(f32x4*)&a8[4];
    }
    __syncthreads();
    if (t < 128)
      g_w20[t] = s_red[t] + s_red[128 + t] + s_red[256 + t] + s_red[384 + t];
  }
}

// ---- w2 = h @ W_m for all graphs (M=2048, N=128, K=512), 64x64 tiles.
// hsel 0: h from g_Acat h-half (stride 640). hsel 1: h from g_h3 (stride 512). ----
__global__ __launch_bounds__(256) void k_w2(int hsel) {
  alignas(16) __shared__ u16 As[64 * 64];
  alignas(16) __shared__ u16 Bs[64 * 64];
  const int t = threadIdx.x, lid = t & 63, w = t >> 6;
  const int m0 = blockIdx.x * 64, n0 = blockIdx.y * 64;
  const int rr = lid & 15, quad = lid >> 4;
  const int rsub = lid >> 3;
  const int cs = (lid & 7) ^ rsub;
  const int wm = (w >> 1) * 32, wn = (w & 1) * 32;
  const u16* Ap = hsel ? g_h3 : g_Acat;
  const int astr = hsel ? 512 : 640;
  f32x4 acc[2][2] = {};
  for (int kt = 0; kt < 8; ++kt) {
    const int k0 = kt * 64;
    GLD16(Ap + (size_t)(m0 + w * 16 + rsub) * astr + k0 + cs * 8, As + (w * 16) * 64);
    GLD16(Ap + (size_t)(m0 + w * 16 + 8 + rsub) * astr + k0 + cs * 8, As + (w * 16 + 8) * 64);
    GLD16(g_wmT + (size_t)(n0 + w * 16 + rsub) * 512 + k0 + cs * 8, Bs + (w * 16) * 64);
    GLD16(g_wmT + (size_t)(n0 + w * 16 + 8 + rsub) * 512 + k0 + cs * 8, Bs + (w * 16 + 8) * 64);
    __syncthreads();
#pragma unroll
    for (int kk = 0; kk < 2; ++kk) {
      const int qb = kk * 4 + quad;
      const int sw = (qb ^ (rr & 7)) << 3;
      half8 af[2], bfr[2];
#pragma unroll
      for (int i = 0; i < 2; ++i) af[i]  = *(const half8*)(As + (wm + i * 16 + rr) * 64 + sw);
#pragma unroll
      for (int j = 0; j < 2; ++j) bfr[j] = *(const half8*)(Bs + (wn + j * 16 + rr) * 64 + sw);
#pragma unroll
      for (int i = 0; i < 2; ++i)
#pragma unroll
        for (int j = 0; j < 2; ++j)
          acc[i][j] = __builtin_amdgcn_mfma_f32_16x16x32_f16(bfr[j], af[i], acc[i][j], 0, 0, 0);
    }
    __syncthreads();
  }
#pragma unroll
  for (int i = 0; i < 2; ++i)
#pragma unroll
    for (int j = 0; j < 2; ++j) {
      const int row = m0 + wm + i * 16 + rr;
      const int c0 = n0 + wn + j * 16 + quad * 4;
      *(f32x4*)(g_w2 + (size_t)row * DIM + c0) = acc[i][j];
    }
}

// ---- gates GEMM (one 64x64 tile per block) + fused LSTM epilogue.
// h3out=0: new h -> g_Acat h-half (A-reads touch only S' cols, aoff=512).
// h3out=1: new h -> g_h3 (A-reads cover h cols; separate buffer, no race). ----
__global__ __launch_bounds__(256) void k_gemm(int ktiles2, int aoff, int useGh,
                                              int first, int wout, int h3out,
                                              void* __restrict__ out) {
  alignas(16) __shared__ u16 As[2][64 * 64];
  alignas(16) __shared__ u16 Bs[2][64 * 64];
  const int t = threadIdx.x, lid = t & 63, w = t >> 6;
  const int m0 = (blockIdx.x & 31) * 64, n0 = (blockIdx.x >> 5) * 64;
  const int rr = lid & 15, quad = lid >> 4;
  const int rsub = lid >> 3;
  const int cs = (lid & 7) ^ rsub;
  const int wm = (w >> 1) * 32, wn = (w & 1) * 32;
  const int isb = g_isbf16;
  f32x4 acc[2][2] = {};
  for (int kt2 = 0; kt2 < ktiles2; ++kt2) {
#pragma unroll
    for (int b = 0; b < 2; ++b) {
      const int k0 = aoff + (kt2 * 2 + b) * 64;
      GLD16(g_Acat + (size_t)(m0 + w * 16 + rsub) * 640 + k0 + cs * 8, As[b] + (w * 16) * 64);
      GLD16(g_Acat + (size_t)(m0 + w * 16 + 8 + rsub) * 640 + k0 + cs * 8, As[b] + (w * 16 + 8) * 64);
      GLD16(g_wgf  + (size_t)(n0 + w * 16 + rsub) * 640 + k0 + cs * 8, Bs[b] + (w * 16) * 64);
      GLD16(g_wgf  + (size_t)(n0 + w * 16 + 8 + rsub) * 640 + k0 + cs * 8, Bs[b] + (w * 16 + 8) * 64);
    }
    __syncthreads();
#pragma unroll
    for (int b = 0; b < 2; ++b)
#pragma unroll
      for (int kk = 0; kk < 2; ++kk) {
        const int qb = kk * 4 + quad;
        const int sw = (qb ^ (rr & 7)) << 3;
        half8 af[2], bfr[2];
#pragma unroll
        for (int i = 0; i < 2; ++i) af[i]  = *(const half8*)(As[b] + (wm + i * 16 + rr) * 64 + sw);
#pragma unroll
        for (int j = 0; j < 2; ++j) bfr[j] = *(const half8*)(Bs[b] + (wn + j * 16 + rr) * 64 + sw);
#pragma unroll
        for (int i = 0; i < 2; ++i)
#pragma unroll
          for (int j = 0; j < 2; ++j)
            acc[i][j] = __builtin_amdgcn_mfma_f32_16x16x32_f16(bfr[j], af[i], acc[i][j], 0, 0, 0);
      }
    __syncthreads();
  }
#pragma unroll
  for (int i = 0; i < 2; ++i) {
    const int row = m0 + wm + i * 16 + rr;           // graph
    const float tp = g_tp[row];
#pragma unroll
    for (int j = 0; j < 2; ++j) {
      const int c0 = n0 + wn + j * 16 + quad * 4;    // permuted gate col, %4==0
      const int jj = c0 >> 2;                        // hidden index
      float4 bc = *(const float4*)(g_bc + c0);
      float4 bf = *(const float4*)(g_bf + c0);
      float gx = 0.f, gy = 0.f, gz = 0.f, gw = 0.f;
      if (useGh) {
        float4 gh = *(const float4*)(g_gh + c0);
        gx = gh.x; gy = gh.y; gz = gh.z; gw = gh.w;
      }
      float xi = acc[i][j][0] + bc.x + gx + tp * bf.x;
      float xf = acc[i][j][1] + bc.y + gy + tp * bf.y;
      float xg = acc[i][j][2] + bc.z + gz + tp * bf.z;
      float xo = acc[i][j][3] + bc.w + gw + tp * bf.w;
      float si = 1.f / (1.f + __expf(-xi));
      float sf = 1.f / (1.f + __expf(-xf));
      float tg = tanhf(xg);
      float so = 1.f / (1.f + __expf(-xo));
      float cp = first ? g_c0[jj] : g_c[(size_t)row * 512 + jj];
      float cn = sf * cp + si * tg;
      float hn = so * tanhf(cn);
      g_c[(size_t)row * 512 + jj] = cn;
      if (h3out) g_h3[(size_t)row * 512 + jj] = f2h(hn);
      else       g_Acat[(size_t)row * 640 + jj] = f2h(hn);
      if (wout) {
        if (isb) ((u16*)out)[(size_t)row * 1024 + jj] = f2bf(hn);
        else     ((float*)out)[(size_t)row * 1024 + jj] = hn;
      }
    }
  }
}

// ---- attention: one graph per block. Pure feature scan (w2 precomputed).
// w2sel 0: w2 = g_w20 (iter 1, graph-independent). w2sel 1: w2 = g_w2[g].
// fin=0: S' fp16 -> Acat, t' -> g_tp. fin=1: r = S'@W_m^T + t'*b_m -> out
// (coalesced g_wmT reads). ----
__global__ __launch_bounds__(256) void k_attn(const void* __restrict__ feat,
                                              int w2sel, int fin,
                                              void* __restrict__ out,
                                              const void* __restrict__ bm) {
  __shared__ float s_m[4], s_l[4];
  __shared__ float s_s[4][DIM];
  __shared__ float s_keep[DIM];
  __shared__ float s_tpv[1];
  const int g = blockIdx.x;
  const int t = threadIdx.x, lid = t & 63, wid = t >> 6;
  const int c = lid & 15;                          // 8-col chunk index
  const int slot = lid >> 4;                       // node slot 0..3
  const int israw = g_isbf16;
  const int s = g_start[g], e = g_start[g + 1];
  float w2r[8];
  if (w2sel) {
    *(float4*)(w2r)     = *(const float4*)(g_w2 + (size_t)g * DIM + c * 8);
    *(float4*)(w2r + 4) = *(const float4*)(g_w2 + (size_t)g * DIM + c * 8 + 4);
  } else {
    *(float4*)(w2r)     = *(const float4*)(g_w20 + c * 8);
    *(float4*)(w2r + 4) = *(const float4*)(g_w20 + c * 8 + 4);
  }
  float mrun = -3.0e38f, lsum = 0.f;
  float racc[8] = {0.f, 0.f, 0.f, 0.f, 0.f, 0.f, 0.f, 0.f};
  for (int nb = s + wid * 4; nb < e; nb += 16) {   // 4 waves x 4 slots
    const int n = nb + slot;
    float fv[8], d;
    if (n < e) {
      if (israw) {
        uint4 q = *(const uint4*)((const u16*)feat + (size_t)n * DIM + c * 8);
        fv[0] = u2f_lo(q.x); fv[1] = u2f_hi(q.x);
        fv[2] = u2f_lo(q.y); fv[3] = u2f_hi(q.y);
        fv[4] = u2f_lo(q.z); fv[5] = u2f_hi(q.z);
        fv[6] = u2f_lo(q.w); fv[7] = u2f_hi(q.w);
      } else {
        const float* fp = (const float*)feat + (size_t)n * DIM + c * 8;
        float4 f0 = *(const float4*)fp;
        float4 f1 = *(const float4*)(fp + 4);
        fv[0] = f0.x; fv[1] = f0.y; fv[2] = f0.z; fv[3] = f0.w;
        fv[4] = f1.x; fv[5] = f1.y; fv[6] = f1.z; fv[7] = f1.w;
      }
      d = 0.f;
#pragma unroll
      for (int j = 0; j < 8; ++j) d += fv[j] * w2r[j];
    } else {
      d = -1.0e30f;                                // poison: slot inactive
#pragma unroll
      for (int j = 0; j < 8; ++j) fv[j] = 0.f;
    }
#pragma unroll
    for (int o = 1; o < 16; o <<= 1) d += __shfl_xor(d, o, 64);
    float m4 = fmaxf(d, __shfl_xor(d, 16, 64));
    m4 = fmaxf(m4, __shfl_xor(m4, 32, 64));
    float mnew = fmaxf(mrun, m4);
    float sc = __expf(mrun - mnew);
    float w = __expf(d - mnew);
    lsum = lsum * sc + w;
#pragma unroll
    for (int j = 0; j < 8; ++j) racc[j] = racc[j] * sc + w * fv[j];
    mrun = mnew;
  }
  float lt = lsum + __shfl_xor(lsum, 16, 64);
  lt += __shfl_xor(lt, 32, 64);
#pragma unroll
  for (int j = 0; j < 8; ++j) {
    racc[j] += __shfl_xor(racc[j], 16, 64);
    racc[j] += __shfl_xor(racc[j], 32, 64);
  }
  if (lid == 0) s_m[wid] = mrun;
  __syncthreads();
  float gmax = fmaxf(fmaxf(s_m[0], s_m[1]), fmaxf(s_m[2], s_m[3]));
  float scw = __expf(mrun - gmax);                 // wave-uniform
  if (lid < 16) {
    float4 lo = make_float4(racc[0] * scw, racc[1] * scw, racc[2] * scw, racc[3] * scw);
    float4 hi = make_float4(racc[4] * scw, racc[5] * scw, racc[6] * scw, racc[7] * scw);
    *(f32x4*)&s_s[wid][c * 8] = *(f32x4*)&lo;
    *(f32x4*)&s_s[wid][c * 8 + 4] = *(f32x4*)&hi;
  }
  if (lid == 0) s_l[wid] = lt * scw;
  __syncthreads();
  float total = s_l[0] + s_l[1] + s_l[2] + s_l[3];
  float inv = 1.f / (total + 1e-7f);
  if (!fin) {
    if (t == 0) g_tp[g] = total * inv;
    if (t < 64) {
      int d0 = t * 2;
      float v0 = (s_s[0][d0] + s_s[1][d0] + s_s[2][d0] + s_s[3][d0]) * inv;
      float v1 = (s_s[0][d0 + 1] + s_s[1][d0 + 1] + s_s[2][d0 + 1] + s_s[3][d0 + 1]) * inv;
      ((unsigned*)g_Acat)[(size_t)g * 320 + 256 + t] =
          (unsigned)f2h(v0) | ((unsigned)f2h(v1) << 16);
    }
  } else {
    if (t == 0) s_tpv[0] = total * inv;
    if (t < 64) {
      int d0 = t * 2;
      s_keep[d0]     = (s_s[0][d0] + s_s[1][d0] + s_s[2][d0] + s_s[3][d0]) * inv;
      s_keep[d0 + 1] = (s_s[0][d0 + 1] + s_s[1][d0 + 1] + s_s[2][d0 + 1] + s_s[3][d0 + 1]) * inv;
    }
    __syncthreads();
    // r[2t], r[2t+1] from g_wmT: lane t reads u32 at [d*256 + t] -> cols 2t,2t+1
    // of row d. Lanes consecutive -> fully coalesced per d.
    const int jj = t * 2;
    const unsigned* wt = (const unsigned*)g_wmT;
    float a0 = 0.f, a1 = 0.f;
#pragma unroll 8
    for (int d = 0; d < 128; ++d) {
      unsigned pr = wt[d * 256 + t];
      float kv = s_keep[d];
      a0 += kv * h2f((u16)pr);
      a1 += kv * h2f((u16)(pr >> 16));
    }
    float tp = s_tpv[0];
    float r0 = a0 + tp * rdf(bm, jj);
    float r1 = a1 + tp * rdf(bm, jj + 1);
    if (israw) {
      ((unsigned*)out)[((size_t)g * 1024 + 512 + jj) >> 1] =
          (unsigned)f2bf(r0) | ((unsigned)f2bf(r1) << 16);
    } else {
      *(float2*)((float*)out + (size_t)g * 1024 + 512 + jj) = make_float2(r0, r1);
    }
  }
}

extern "C" void kernel_launch(void* const* d_in, const int* in_sizes, int n_in,
                              void* d_out, int out_size, void* d_ws, size_t ws_size,
                              hipStream_t stream) {
  const void* features = d_in[0];
  const void* gidx     = d_in[1];
  const void* W_m      = d_in[2];
  const void* b_m      = d_in[3];
  const void* W_ih     = d_in[4];
  const void* W_hh     = d_in[5];
  const void* b_ih     = d_in[6];
  const void* b_hh     = d_in[7];

  k_s0<<<1024, 256, 0, stream>>>(features, gidx, W_m, W_ih, W_hh);
  k_s1<<<193, 256, 0, stream>>>(b_ih, b_hh, b_m);
  // iter 1 attention (h1 graph-independent, w2 = w20)
  k_attn<<<NG, 256, 0, stream>>>(features, 0, 0, d_out, b_m);
  // iter 2: gates = gh + bc + t'*bf + S'@Wfold^T (K=128) -> h2 in Acat
  k_gemm<<<1024, 256, 0, stream>>>(1, 512, 1, 1, 0, 0, d_out);
  k_w2<<<dim3(32, 2), 256, 0, stream>>>(0);        // w2 = h2 @ W_m
  k_attn<<<NG, 256, 0, stream>>>(features, 1, 0, d_out, b_m);
  // iter 3: full K=640 gates GEMM -> h3 (separate buffer) + h-half of out
  k_gemm<<<1024, 256, 0, stream>>>(5, 0, 0, 0, 1, 1, d_out);
  k_w2<<<dim3(32, 2), 256, 0, stream>>>(1);        // w2 = h3 @ W_m
  // iter 3 attention + r epilogue -> out cols 512..1023
  k_attn<<<NG, 256, 0, stream>>>(features, 1, 1, d_out, b_m);
}